// Round 7
// baseline (475.325 us; speedup 1.0000x reference)
//
#include <hip/hip_runtime.h>

#define H 1024
#define S 2048
#define B 32
#define M (S*B)

typedef short bf16x8 __attribute__((ext_vector_type(8)));
typedef float f32x4 __attribute__((ext_vector_type(4)));

__device__ __forceinline__ unsigned short f2bf(float f) {
    unsigned int u = __builtin_bit_cast(unsigned int, f);
    u += 0x7FFFu + ((u >> 16) & 1u);
    return (unsigned short)(u >> 16);
}

__device__ __forceinline__ void gload_lds16(const void* g, void* l) {
    __builtin_amdgcn_global_load_lds((const __attribute__((address_space(1))) void*)g,
                                     (__attribute__((address_space(3))) void*)l, 16, 0, 0);
}

// ---------------- enc f32 -> bf16 ----------------
__global__ __launch_bounds__(256) void convert_enc(const float* __restrict__ enc,
                                                   unsigned short* __restrict__ encBF) {
    const size_t total = (size_t)M * H / 8;
    for (size_t idx = (size_t)blockIdx.x * 256 + threadIdx.x; idx < total;
         idx += (size_t)gridDim.x * 256) {
        const float4* p = (const float4*)(enc + idx * 8);
        float4 x = p[0], y = p[1];
        bf16x8 c;
        c[0] = (short)f2bf(x.x); c[1] = (short)f2bf(x.y);
        c[2] = (short)f2bf(x.z); c[3] = (short)f2bf(x.w);
        c[4] = (short)f2bf(y.x); c[5] = (short)f2bf(y.y);
        c[6] = (short)f2bf(y.z); c[7] = (short)f2bf(y.w);
        *(bf16x8*)(encBF + idx * 8) = c;
    }
}

// ---------------- We -> We^T (bf16) ----------------
__global__ __launch_bounds__(256) void transpose_we(const float* __restrict__ We,
                                                    unsigned short* __restrict__ WeT) {
    __shared__ float t[64][65];
    int tx = threadIdx.x & 63, ty = threadIdx.x >> 6;
    int n0 = blockIdx.x * 64, k0 = blockIdx.y * 64;
#pragma unroll
    for (int q = 0; q < 16; ++q) {
        int kk = ty * 16 + q;
        t[kk][tx] = We[(size_t)(k0 + kk) * H + n0 + tx];
    }
    __syncthreads();
#pragma unroll
    for (int q = 0; q < 16; ++q) {
        int nn = ty * 16 + q;
        WeT[(size_t)(n0 + nn) * H + k0 + tx] = f2bf(t[tx][nn]);
    }
}

// ---------------- d[b][j] = dec[b] @ Wd ----------------
__global__ __launch_bounds__(256) void dec_proj(const float* __restrict__ dec,
                                                const float* __restrict__ Wd,
                                                float* __restrict__ dvec) {
    __shared__ float ds[H];
    int b = blockIdx.y, jc = blockIdx.x, t = threadIdx.x;
    for (int i = t; i < H; i += 256) ds[i] = dec[b * H + i];
    __syncthreads();
    int j = jc * 256 + t;
    float acc = 0.f;
#pragma unroll 8
    for (int h = 0; h < H; ++h) acc += ds[h] * Wd[(size_t)h * H + j];
    dvec[b * H + j] = acc;
}

// ---------------- 256x256 8-phase fused GEMM (faithful m201 port) ----------------
// Per-wave output INTERLEAVED across halves: rows MG*128+wm*64+mi*16,
// cols NG*128+wn*32+ni*16 -> phase (MG,NG) reads ONLY A-half MG, B-half NG.
// LDS per operand: [buf 2][half 2][row 128][64 bf16] (128-B rows),
// physslot = logslot ^ (row&7) (R3's measured-0-conflict pattern);
// global_load_lds dest linear+wave-uniform, SOURCE pre-swizzled (rule 21).
// Stage order per tile t -> t+1: p1:A0 p2:B0 p3:B1 p4:A1.
// Counted waits: vmcnt(2) @p1, vmcnt(4) @p4 (ledger: every half retires
// exactly one phase before first read; 4-8 loads always in flight).
template<int BUF, int MG, int NG, int STG, int SHALF, int WAITN>
__device__ __forceinline__ void phase8(unsigned short* As, unsigned short* Bs,
                                       const unsigned short* aSrc, const unsigned short* bSrc,
                                       int ktNext, int dstw, int l15, int l4, int wm, int wn,
                                       f32x4 (&acc)[8][4]) {
    bf16x8 a[4][2], b[2][2];
#pragma unroll
    for (int mi = 0; mi < 4; ++mi) {
        int r = wm * 64 + mi * 16 + l15;
#pragma unroll
        for (int kk = 0; kk < 2; ++kk)
            a[mi][kk] = *(const bf16x8*)&As[BUF * 16384 + MG * 8192 + r * 64 +
                                            (((kk * 4 + l4) ^ (r & 7)) * 8)];
    }
#pragma unroll
    for (int ni = 0; ni < 2; ++ni) {
        int r = wn * 32 + ni * 16 + l15;
#pragma unroll
        for (int kk = 0; kk < 2; ++kk)
            b[ni][kk] = *(const bf16x8*)&Bs[BUF * 16384 + NG * 8192 + r * 64 +
                                            (((kk * 4 + l4) ^ (r & 7)) * 8)];
    }
    if (STG == 1) {
#pragma unroll
        for (int q = 0; q < 2; ++q)
            gload_lds16(aSrc + ((size_t)(SHALF * 128 + q * 64)) * H + ktNext * 64,
                        &As[(BUF ^ 1) * 16384 + SHALF * 8192 + q * 4096 + dstw]);
    }
    if (STG == 2) {
#pragma unroll
        for (int q = 0; q < 2; ++q)
            gload_lds16(bSrc + ((size_t)(SHALF * 128 + q * 64)) * H + ktNext * 64,
                        &Bs[(BUF ^ 1) * 16384 + SHALF * 8192 + q * 4096 + dstw]);
    }
    __builtin_amdgcn_s_barrier();
    __builtin_amdgcn_s_setprio(1);
#pragma unroll
    for (int mi = 0; mi < 4; ++mi)
#pragma unroll
        for (int ni = 0; ni < 2; ++ni)
#pragma unroll
            for (int kk = 0; kk < 2; ++kk)
                acc[MG * 4 + mi][NG * 2 + ni] = __builtin_amdgcn_mfma_f32_16x16x32_bf16(
                    a[mi][kk], b[ni][kk], acc[MG * 4 + mi][NG * 2 + ni], 0, 0, 0);
    __builtin_amdgcn_s_setprio(0);
    if constexpr (WAITN >= 0)
        asm volatile("s_waitcnt vmcnt(%0)" :: "n"(WAITN) : "memory");
    __builtin_amdgcn_s_barrier();
}

__global__ __launch_bounds__(512) void gemm_logits5(const unsigned short* __restrict__ encBF,
                                                    const unsigned short* __restrict__ WeT,
                                                    const float* __restrict__ dvec,
                                                    const float* __restrict__ v,
                                                    float* __restrict__ part) {
    __shared__ unsigned short As[32768];   // 64 KB: [2 buf][2 half][128][64]
    __shared__ unsigned short Bs[32768];   // 64 KB
    int tid = threadIdx.x, bid = blockIdx.x;
    int swz = (bid & 7) * 128 + (bid >> 3);   // XCD-chunked, bijective (1024 % 8 == 0)
    int bm = swz >> 2, bn = swz & 3;
    int lane = tid & 63, wid = tid >> 6;
    int wm = wid >> 2, wn = wid & 3;
    int l15 = lane & 15, l4 = lane >> 4;

    f32x4 acc[8][4] = {};

    // staging: thread t -> chunk row t>>3, physslot t&7; source col pre-swizzled.
    int srow = tid >> 3;                       // 0..63 within 8-KB chunk
    int gslot = (tid & 7) ^ (srow & 7);
    const unsigned short* aSrc = encBF + (size_t)(bm * 256 + srow) * H + gslot * 8;
    const unsigned short* bSrc = WeT + (size_t)(bn * 256 + srow) * H + gslot * 8;
    int dstw = __builtin_amdgcn_readfirstlane((tid >> 6) << 9);  // wave-uniform LDS offset

    // prologue: stage all 4 halves of K-tile 0 into buf0; drain; barrier.
#pragma unroll
    for (int hf = 0; hf < 2; ++hf)
#pragma unroll
        for (int q = 0; q < 2; ++q) {
            gload_lds16(aSrc + ((size_t)(hf * 128 + q * 64)) * H, &As[hf * 8192 + q * 4096 + dstw]);
            gload_lds16(bSrc + ((size_t)(hf * 128 + q * 64)) * H, &Bs[hf * 8192 + q * 4096 + dstw]);
        }
    asm volatile("s_waitcnt vmcnt(0)" ::: "memory");
    __builtin_amdgcn_s_barrier();

    for (int it = 0; it < 7; ++it) {
        int kA = 2 * it + 1, kB = 2 * it + 2;
        // tile 2it (buf0), staging tile 2it+1 -> buf1
        phase8<0,0,0, 1,0, 2>(As, Bs, aSrc, bSrc, kA, dstw, l15, l4, wm, wn, acc);
        phase8<0,0,1, 2,0,-1>(As, Bs, aSrc, bSrc, kA, dstw, l15, l4, wm, wn, acc);
        phase8<0,1,0, 2,1,-1>(As, Bs, aSrc, bSrc, kA, dstw, l15, l4, wm, wn, acc);
        phase8<0,1,1, 1,1, 4>(As, Bs, aSrc, bSrc, kA, dstw, l15, l4, wm, wn, acc);
        // tile 2it+1 (buf1), staging tile 2it+2 -> buf0
        phase8<1,0,0, 1,0, 2>(As, Bs, aSrc, bSrc, kB, dstw, l15, l4, wm, wn, acc);
        phase8<1,0,1, 2,0,-1>(As, Bs, aSrc, bSrc, kB, dstw, l15, l4, wm, wn, acc);
        phase8<1,1,0, 2,1,-1>(As, Bs, aSrc, bSrc, kB, dstw, l15, l4, wm, wn, acc);
        phase8<1,1,1, 1,1, 4>(As, Bs, aSrc, bSrc, kB, dstw, l15, l4, wm, wn, acc);
    }
    // tile 14 (buf0), staging tile 15 -> buf1
    phase8<0,0,0, 1,0, 2>(As, Bs, aSrc, bSrc, 15, dstw, l15, l4, wm, wn, acc);
    phase8<0,0,1, 2,0,-1>(As, Bs, aSrc, bSrc, 15, dstw, l15, l4, wm, wn, acc);
    phase8<0,1,0, 2,1,-1>(As, Bs, aSrc, bSrc, 15, dstw, l15, l4, wm, wn, acc);
    phase8<0,1,1, 1,1, 4>(As, Bs, aSrc, bSrc, 15, dstw, l15, l4, wm, wn, acc);
    // tile 15 (buf1), no staging; tail drains 2 -> 0
    phase8<1,0,0, 0,0, 2>(As, Bs, aSrc, bSrc, 0, dstw, l15, l4, wm, wn, acc);
    phase8<1,0,1, 0,0, 0>(As, Bs, aSrc, bSrc, 0, dstw, l15, l4, wm, wn, acc);
    phase8<1,1,0, 0,0,-1>(As, Bs, aSrc, bSrc, 0, dstw, l15, l4, wm, wn, acc);
    phase8<1,1,1, 0,0,-1>(As, Bs, aSrc, bSrc, 0, dstw, l15, l4, wm, wn, acc);

    // epilogue: partial logit over this wave's 64 j's (2 NG x 2 ni x 16 lanes)
    float vj[2][2];
#pragma unroll
    for (int g = 0; g < 2; ++g)
#pragma unroll
        for (int ni = 0; ni < 2; ++ni)
            vj[g][ni] = v[bn * 256 + g * 128 + wn * 32 + ni * 16 + l15];
#pragma unroll
    for (int g = 0; g < 2; ++g) {
#pragma unroll
        for (int mi = 0; mi < 4; ++mi) {
#pragma unroll
            for (int i = 0; i < 4; ++i) {
                int rg = bm * 256 + g * 128 + wm * 64 + mi * 16 + l4 * 4 + i;
                int bb = rg & (B - 1);   // row = s*B + b
                float p = 0.f;
#pragma unroll
                for (int ng = 0; ng < 2; ++ng)
#pragma unroll
                    for (int ni = 0; ni < 2; ++ni) {
                        int j = bn * 256 + ng * 128 + wn * 32 + ni * 16 + l15;
                        p += vj[ng][ni] * tanhf(dvec[bb * H + j] + acc[g * 4 + mi][ng * 2 + ni][i]);
                    }
                p += __shfl_xor(p, 1);
                p += __shfl_xor(p, 2);
                p += __shfl_xor(p, 4);
                p += __shfl_xor(p, 8);
                if (l15 == 0) part[(size_t)rg * 16 + bn * 4 + wn] = p;
            }
        }
    }
}

// ---------------- softmax over s per b ----------------
__global__ __launch_bounds__(256) void softmax_k(const float* __restrict__ part,
                                                 float* __restrict__ scores) {
    int b = blockIdx.x, tid = threadIdx.x;
    int lane = tid & 63, wid = tid >> 6;
    __shared__ float red[4];
    __shared__ float red2[4];
    float lg[8];
    float mx = -1e30f;
#pragma unroll
    for (int q = 0; q < 8; ++q) {
        int s = q * 256 + tid;
        const float4* pr = (const float4*)(part + ((size_t)(s * B + b)) * 16);
        float4 x = pr[0], y = pr[1], z = pr[2], w = pr[3];
        float L = (((x.x + x.y) + (x.z + x.w)) + ((y.x + y.y) + (y.z + y.w))) +
                  (((z.x + z.y) + (z.z + z.w)) + ((w.x + w.y) + (w.z + w.w)));
        lg[q] = L;
        mx = fmaxf(mx, L);
    }
#pragma unroll
    for (int off = 32; off; off >>= 1) mx = fmaxf(mx, __shfl_xor(mx, off));
    if (lane == 0) red[wid] = mx;
    __syncthreads();
    mx = fmaxf(fmaxf(red[0], red[1]), fmaxf(red[2], red[3]));
    float sum = 0.f;
#pragma unroll
    for (int q = 0; q < 8; ++q) {
        lg[q] = expf(lg[q] - mx);
        sum += lg[q];
    }
#pragma unroll
    for (int off = 32; off; off >>= 1) sum += __shfl_xor(sum, off);
    if (lane == 0) red2[wid] = sum;
    __syncthreads();
    sum = (red2[0] + red2[1]) + (red2[2] + red2[3]);
    float inv = 1.f / sum;
#pragma unroll
    for (int q = 0; q < 8; ++q) scores[b * S + q * 256 + tid] = lg[q] * inv;
}

// ---------------- attn_values partials: sum over an S-chunk ----------------
__global__ __launch_bounds__(256) void weighted_sum(const float* __restrict__ enc,
                                                    const float* __restrict__ scores,
                                                    float* __restrict__ part2) {
    __shared__ float sl[512];
    int t = threadIdx.x;
    int hx = blockIdx.x, b = blockIdx.y, sc = blockIdx.z;
    sl[t] = scores[b * S + sc * 512 + t];
    sl[t + 256] = scores[b * S + sc * 512 + t + 256];
    __syncthreads();
    int h = hx * 256 + t;
    const float* ep = enc + ((size_t)(sc * 512) * B) * H + (size_t)b * H + h;
    float acc = 0.f;
#pragma unroll 4
    for (int s = 0; s < 512; ++s) acc += ep[(size_t)s * B * H] * sl[s];
    part2[((size_t)sc * B + b) * H + h] = acc;
}

__global__ __launch_bounds__(256) void reduce_vals(const float* __restrict__ part2,
                                                   float* __restrict__ out) {
    int i = blockIdx.x * 256 + threadIdx.x;
    out[i] = (part2[i] + part2[B * H + i]) + (part2[2 * B * H + i] + part2[3 * B * H + i]);
}

extern "C" void kernel_launch(void* const* d_in, const int* in_sizes, int n_in,
                              void* d_out, int out_size, void* d_ws, size_t ws_size,
                              hipStream_t stream) {
    const float* dec = (const float*)d_in[0];   // [1,B,H]
    const float* enc = (const float*)d_in[1];   // [S,B,H]
    const float* Wd  = (const float*)d_in[2];   // [H,H]
    const float* We  = (const float*)d_in[3];   // [H,H]
    const float* v   = (const float*)d_in[4];   // [H]
    float* out = (float*)d_out;                 // [B*H] values, then [B*S] scores

    char* ws = (char*)d_ws;
    unsigned short* WeT = (unsigned short*)ws;                 // 2 MB
    float* dvec  = (float*)(ws + (2u << 20));                  // 128 KB
    float* part  = (float*)(ws + (3u << 20));                  // 4 MB
    float* part2 = (float*)(ws + (7u << 20));                  // 512 KB
    unsigned short* encBF = (unsigned short*)(ws + ((size_t)8 << 20));  // 128 MB

    transpose_we<<<dim3(16, 16), 256, 0, stream>>>(We, WeT);
    dec_proj<<<dim3(4, B), 256, 0, stream>>>(dec, Wd, dvec);
    convert_enc<<<2048, 256, 0, stream>>>(enc, encBF);
    gemm_logits5<<<1024, 512, 0, stream>>>(encBF, WeT, dvec, v, part);
    softmax_k<<<B, 256, 0, stream>>>(part, out + B * H);
    weighted_sum<<<dim3(4, B, 4), 256, 0, stream>>>(enc, out + B * H, part2);
    reduce_vals<<<128, 256, 0, stream>>>(part2, out);
}

// Round 8
// 367.884 us; speedup vs baseline: 1.2921x; 1.2921x over previous
//
#include <hip/hip_runtime.h>

#define H 1024
#define S 2048
#define B 32
#define M (S*B)
#define NSC 16   // S-chunks for weighted_sum

typedef short bf16x8 __attribute__((ext_vector_type(8)));
typedef float f32x4 __attribute__((ext_vector_type(4)));

__device__ __forceinline__ unsigned short f2bf(float f) {
    unsigned int u = __builtin_bit_cast(unsigned int, f);
    u += 0x7FFFu + ((u >> 16) & 1u);
    return (unsigned short)(u >> 16);
}

__device__ __forceinline__ float tanh_fast(float x) {
    // 1 - 2/(e^{2x}+1); handles +-inf saturation correctly via v_exp_f32
    float e = __expf(2.f * x);
    return 1.f - 2.f / (e + 1.f);
}

__device__ __forceinline__ void gload_lds16(const void* g, void* l) {
    __builtin_amdgcn_global_load_lds((const __attribute__((address_space(1))) void*)g,
                                     (__attribute__((address_space(3))) void*)l, 16, 0, 0);
}

// ---------------- enc f32 -> bf16 ----------------
__global__ __launch_bounds__(256) void convert_enc(const float* __restrict__ enc,
                                                   unsigned short* __restrict__ encBF) {
    const size_t total = (size_t)M * H / 8;
    for (size_t idx = (size_t)blockIdx.x * 256 + threadIdx.x; idx < total;
         idx += (size_t)gridDim.x * 256) {
        const float4* p = (const float4*)(enc + idx * 8);
        float4 x = p[0], y = p[1];
        bf16x8 c;
        c[0] = (short)f2bf(x.x); c[1] = (short)f2bf(x.y);
        c[2] = (short)f2bf(x.z); c[3] = (short)f2bf(x.w);
        c[4] = (short)f2bf(y.x); c[5] = (short)f2bf(y.y);
        c[6] = (short)f2bf(y.z); c[7] = (short)f2bf(y.w);
        *(bf16x8*)(encBF + idx * 8) = c;
    }
}

// ---------------- We -> We^T (bf16) ----------------
__global__ __launch_bounds__(256) void transpose_we(const float* __restrict__ We,
                                                    unsigned short* __restrict__ WeT) {
    __shared__ float t[64][65];
    int tx = threadIdx.x & 63, ty = threadIdx.x >> 6;
    int n0 = blockIdx.x * 64, k0 = blockIdx.y * 64;
#pragma unroll
    for (int q = 0; q < 16; ++q) {
        int kk = ty * 16 + q;
        t[kk][tx] = We[(size_t)(k0 + kk) * H + n0 + tx];
    }
    __syncthreads();
#pragma unroll
    for (int q = 0; q < 16; ++q) {
        int nn = ty * 16 + q;
        WeT[(size_t)(n0 + nn) * H + k0 + tx] = f2bf(t[tx][nn]);
    }
}

// ---------------- d[b][j] = dec[b] @ Wd ----------------
__global__ __launch_bounds__(256) void dec_proj(const float* __restrict__ dec,
                                                const float* __restrict__ Wd,
                                                float* __restrict__ dvec) {
    __shared__ float ds[H];
    int b = blockIdx.y, jc = blockIdx.x, t = threadIdx.x;
    for (int i = t; i < H; i += 256) ds[i] = dec[b * H + i];
    __syncthreads();
    int j = jc * 256 + t;
    float acc = 0.f;
#pragma unroll 8
    for (int h = 0; h < H; ++h) acc += ds[h] * Wd[(size_t)h * H + j];
    dvec[b * H + j] = acc;
}

// ---------------- m97-structure fused GEMM (R3-proven, fast-tanh epilogue) ----------------
// LDS linear (row, slot) holds global (row, slot ^ (row&7)); ds_read applies the same XOR.
__global__ __launch_bounds__(256) void gemm_logits2(const unsigned short* __restrict__ encBF,
                                                    const unsigned short* __restrict__ WeT,
                                                    const float* __restrict__ dvec,
                                                    const float* __restrict__ v,
                                                    float* __restrict__ part) {
    __shared__ unsigned short As[128 * 64];
    __shared__ unsigned short Bs[128 * 64];
    int tid = threadIdx.x, bid = blockIdx.x;
    int swz = (bid & 7) * 512 + (bid >> 3);   // XCD-chunked, bijective (4096 % 8 == 0)
    int bm = swz >> 3, bn = swz & 7;
    int lane = tid & 63, wid = tid >> 6;
    int wm = wid >> 1, wn = wid & 1;

    f32x4 acc[4][4] = {};

    // chunk c = wid*4+q covers tile rows [c*8, c*8+8); lane l -> row c*8+(l>>3), LDS slot l&7.
    int rsub = lane >> 3;
    int gslot = (lane & 7) ^ rsub;
    const unsigned short* aP[4];
    const unsigned short* bP[4];
    unsigned short* aL[4];
    unsigned short* bL[4];
#pragma unroll
    for (int q = 0; q < 4; ++q) {
        int c = wid * 4 + q;
        int grow = c * 8 + rsub;
        aP[q] = encBF + (size_t)(bm * 128 + grow) * H + gslot * 8;
        bP[q] = WeT + (size_t)(bn * 128 + grow) * H + gslot * 8;
        aL[q] = &As[c * 512];
        bL[q] = &Bs[c * 512];
    }

    for (int kt = 0; kt < 16; ++kt) {
        if (kt) __syncthreads();
#pragma unroll
        for (int q = 0; q < 4; ++q) gload_lds16(aP[q] + kt * 64, aL[q]);
#pragma unroll
        for (int q = 0; q < 4; ++q) gload_lds16(bP[q] + kt * 64, bL[q]);
        __syncthreads();
#pragma unroll
        for (int kh = 0; kh < 2; ++kh) {
            bf16x8 a[4], bfr[4];
#pragma unroll
            for (int m = 0; m < 4; ++m) {
                int row = wm * 64 + m * 16 + (lane & 15);
                int slot = (kh * 4 + (lane >> 4)) ^ (row & 7);
                a[m] = *(const bf16x8*)&As[row * 64 + slot * 8];
            }
#pragma unroll
            for (int n = 0; n < 4; ++n) {
                int row = wn * 64 + n * 16 + (lane & 15);
                int slot = (kh * 4 + (lane >> 4)) ^ (row & 7);
                bfr[n] = *(const bf16x8*)&Bs[row * 64 + slot * 8];
            }
#pragma unroll
            for (int m = 0; m < 4; ++m)
#pragma unroll
                for (int n = 0; n < 4; ++n)
                    acc[m][n] = __builtin_amdgcn_mfma_f32_16x16x32_bf16(a[m], bfr[n], acc[m][n], 0, 0, 0);
        }
    }

    // epilogue: partial logit over this wave's 64 j's = sum_j v[j]*tanh(d[b][j] + e)
    float vj[4];
#pragma unroll
    for (int n = 0; n < 4; ++n) vj[n] = v[bn * 128 + wn * 64 + n * 16 + (lane & 15)];
    float pv[4][4];
#pragma unroll
    for (int m = 0; m < 4; ++m) {
#pragma unroll
        for (int i = 0; i < 4; ++i) {
            int rg = bm * 128 + wm * 64 + m * 16 + (lane >> 4) * 4 + i;
            int bb = rg & (B - 1);   // row = s*B + b
            float p = 0.f;
#pragma unroll
            for (int n = 0; n < 4; ++n) {
                int j = bn * 128 + wn * 64 + n * 16 + (lane & 15);
                p += vj[n] * tanh_fast(dvec[bb * H + j] + acc[m][n][i]);
            }
            p += __shfl_xor(p, 1);
            p += __shfl_xor(p, 2);
            p += __shfl_xor(p, 4);
            p += __shfl_xor(p, 8);
            pv[m][i] = p;
        }
    }
    __syncthreads();
    float* red = (float*)As;
    if (wn == 1) {
#pragma unroll
        for (int m = 0; m < 4; ++m)
#pragma unroll
            for (int i = 0; i < 4; ++i) {
                int rl = wm * 64 + m * 16 + (lane >> 4) * 4 + i;
                if ((lane & 15) == 0) red[rl] = pv[m][i];
            }
    }
    __syncthreads();
    if (wn == 0) {
#pragma unroll
        for (int m = 0; m < 4; ++m)
#pragma unroll
            for (int i = 0; i < 4; ++i) {
                int rl = wm * 64 + m * 16 + (lane >> 4) * 4 + i;
                int rg = bm * 128 + rl;
                if ((lane & 15) == 0) part[(size_t)rg * 8 + bn] = pv[m][i] + red[rl];
            }
    }
}

// ---------------- softmax over s per b ----------------
__global__ __launch_bounds__(256) void softmax_k(const float* __restrict__ part,
                                                 float* __restrict__ scores) {
    int b = blockIdx.x, tid = threadIdx.x;
    int lane = tid & 63, wid = tid >> 6;
    __shared__ float red[4];
    __shared__ float red2[4];
    float lg[8];
    float mx = -1e30f;
#pragma unroll
    for (int q = 0; q < 8; ++q) {
        int s = q * 256 + tid;
        const float4* pr = (const float4*)(part + ((size_t)(s * B + b)) * 8);
        float4 x = pr[0], y = pr[1];
        float L = ((x.x + x.y) + (x.z + x.w)) + ((y.x + y.y) + (y.z + y.w));
        lg[q] = L;
        mx = fmaxf(mx, L);
    }
#pragma unroll
    for (int off = 32; off; off >>= 1) mx = fmaxf(mx, __shfl_xor(mx, off));
    if (lane == 0) red[wid] = mx;
    __syncthreads();
    mx = fmaxf(fmaxf(red[0], red[1]), fmaxf(red[2], red[3]));
    float sum = 0.f;
#pragma unroll
    for (int q = 0; q < 8; ++q) {
        lg[q] = expf(lg[q] - mx);
        sum += lg[q];
    }
#pragma unroll
    for (int off = 32; off; off >>= 1) sum += __shfl_xor(sum, off);
    if (lane == 0) red2[wid] = sum;
    __syncthreads();
    sum = (red2[0] + red2[1]) + (red2[2] + red2[3]);
    float inv = 1.f / sum;
#pragma unroll
    for (int q = 0; q < 8; ++q) scores[b * S + q * 256 + tid] = lg[q] * inv;
}

// ---------------- attn_values partials: sum over an S-chunk of 128 ----------------
__global__ __launch_bounds__(256) void weighted_sum(const float* __restrict__ enc,
                                                    const float* __restrict__ scores,
                                                    float* __restrict__ part2) {
    __shared__ float sl[128];
    int t = threadIdx.x;
    int hx = blockIdx.x, b = blockIdx.y, sc = blockIdx.z;
    if (t < 128) sl[t] = scores[b * S + sc * 128 + t];
    __syncthreads();
    int h = hx * 256 + t;
    const float* ep = enc + ((size_t)(sc * 128) * B) * H + (size_t)b * H + h;
    float acc = 0.f;
#pragma unroll 4
    for (int s = 0; s < 128; ++s) acc += ep[(size_t)s * B * H] * sl[s];
    part2[((size_t)sc * B + b) * H + h] = acc;
}

__global__ __launch_bounds__(256) void reduce_vals(const float* __restrict__ part2,
                                                   float* __restrict__ out) {
    int i = blockIdx.x * 256 + threadIdx.x;
    float a = 0.f;
#pragma unroll
    for (int c = 0; c < NSC; ++c) a += part2[(size_t)c * B * H + i];
    out[i] = a;
}

extern "C" void kernel_launch(void* const* d_in, const int* in_sizes, int n_in,
                              void* d_out, int out_size, void* d_ws, size_t ws_size,
                              hipStream_t stream) {
    const float* dec = (const float*)d_in[0];   // [1,B,H]
    const float* enc = (const float*)d_in[1];   // [S,B,H]
    const float* Wd  = (const float*)d_in[2];   // [H,H]
    const float* We  = (const float*)d_in[3];   // [H,H]
    const float* v   = (const float*)d_in[4];   // [H]
    float* out = (float*)d_out;                 // [B*H] values, then [B*S] scores

    char* ws = (char*)d_ws;
    unsigned short* WeT = (unsigned short*)ws;                 // 2 MB
    float* dvec  = (float*)(ws + (2u << 20));                  // 128 KB
    float* part  = (float*)(ws + (3u << 20));                  // 2 MB (M x 8)
    float* part2 = (float*)(ws + (5u << 20));                  // 2 MB (NSC x B x H)
    unsigned short* encBF = (unsigned short*)(ws + ((size_t)8 << 20));  // 128 MB

    transpose_we<<<dim3(16, 16), 256, 0, stream>>>(We, WeT);
    dec_proj<<<dim3(4, B), 256, 0, stream>>>(dec, Wd, dvec);
    convert_enc<<<4096, 256, 0, stream>>>(enc, encBF);
    gemm_logits2<<<4096, 256, 0, stream>>>(encBF, WeT, dvec, v, part);
    softmax_k<<<B, 256, 0, stream>>>(part, out + B * H);
    weighted_sum<<<dim3(4, B, NSC), 256, 0, stream>>>(enc, out + B * H, part2);
    reduce_vals<<<128, 256, 0, stream>>>(part2, out);
}

// Round 9
// 354.373 us; speedup vs baseline: 1.3413x; 1.0381x over previous
//
#include <hip/hip_runtime.h>

#define H 1024
#define S 2048
#define B 32
#define M (S*B)
#define NSC 32   // S-chunks of 64 for weighted_sum

typedef short bf16x8 __attribute__((ext_vector_type(8)));
typedef float f32x4 __attribute__((ext_vector_type(4)));

__device__ __forceinline__ unsigned short f2bf(float f) {
    unsigned int u = __builtin_bit_cast(unsigned int, f);
    u += 0x7FFFu + ((u >> 16) & 1u);
    return (unsigned short)(u >> 16);
}

__device__ __forceinline__ float tanh_fast(float x) {
    float e = __expf(2.f * x);
    return 1.f - 2.f / (e + 1.f);
}

__device__ __forceinline__ void gload_lds16(const void* g, void* l) {
    __builtin_amdgcn_global_load_lds((const __attribute__((address_space(1))) void*)g,
                                     (__attribute__((address_space(3))) void*)l, 16, 0, 0);
}

// ---------------- fused prep: convert_enc + transpose_we + dec_proj ----------------
// blocks [0,4096): enc f32->bf16; [4096,4352): We->WeT bf16; [4352,4480): dvec
__global__ __launch_bounds__(256) void prep(const float* __restrict__ enc,
                                            unsigned short* __restrict__ encBF,
                                            const float* __restrict__ We,
                                            unsigned short* __restrict__ WeT,
                                            const float* __restrict__ dec,
                                            const float* __restrict__ Wd,
                                            float* __restrict__ dvec) {
    __shared__ float shbuf[64 * 65];
    int bid = blockIdx.x, t = threadIdx.x;
    if (bid < 4096) {
        const size_t total = (size_t)M * H / 8;
        for (size_t idx = (size_t)bid * 256 + t; idx < total; idx += (size_t)4096 * 256) {
            const float4* p = (const float4*)(enc + idx * 8);
            float4 x = p[0], y = p[1];
            bf16x8 c;
            c[0] = (short)f2bf(x.x); c[1] = (short)f2bf(x.y);
            c[2] = (short)f2bf(x.z); c[3] = (short)f2bf(x.w);
            c[4] = (short)f2bf(y.x); c[5] = (short)f2bf(y.y);
            c[6] = (short)f2bf(y.z); c[7] = (short)f2bf(y.w);
            *(bf16x8*)(encBF + idx * 8) = c;
        }
    } else if (bid < 4352) {
        int b2 = bid - 4096;
        int tx = t & 63, ty = t >> 6;
        int n0 = (b2 & 15) * 64, k0 = (b2 >> 4) * 64;
#pragma unroll
        for (int q = 0; q < 16; ++q) {
            int kk = ty * 16 + q;
            shbuf[kk * 65 + tx] = We[(size_t)(k0 + kk) * H + n0 + tx];
        }
        __syncthreads();
#pragma unroll
        for (int q = 0; q < 16; ++q) {
            int nn = ty * 16 + q;
            WeT[(size_t)(n0 + nn) * H + k0 + tx] = f2bf(shbuf[tx * 65 + nn]);
        }
    } else {
        int b3 = bid - 4352;
        int jc = b3 & 3, b = b3 >> 2;
        for (int i = t; i < H; i += 256) shbuf[i] = dec[b * H + i];
        __syncthreads();
        int j = jc * 256 + t;
        float acc = 0.f;
#pragma unroll 8
        for (int h = 0; h < H; ++h) acc += shbuf[h] * Wd[(size_t)h * H + j];
        dvec[b * H + j] = acc;
    }
}

// ---------------- m97-structure fused GEMM (R8-proven) ----------------
__global__ __launch_bounds__(256) void gemm_logits2(const unsigned short* __restrict__ encBF,
                                                    const unsigned short* __restrict__ WeT,
                                                    const float* __restrict__ dvec,
                                                    const float* __restrict__ v,
                                                    float* __restrict__ part) {
    __shared__ unsigned short As[128 * 64];
    __shared__ unsigned short Bs[128 * 64];
    int tid = threadIdx.x, bid = blockIdx.x;
    int swz = (bid & 7) * 512 + (bid >> 3);   // XCD-chunked, bijective (4096 % 8 == 0)
    int bm = swz >> 3, bn = swz & 7;
    int lane = tid & 63, wid = tid >> 6;
    int wm = wid >> 1, wn = wid & 1;

    f32x4 acc[4][4] = {};

    int rsub = lane >> 3;
    int gslot = (lane & 7) ^ rsub;
    const unsigned short* aP[4];
    const unsigned short* bP[4];
    unsigned short* aL[4];
    unsigned short* bL[4];
#pragma unroll
    for (int q = 0; q < 4; ++q) {
        int c = wid * 4 + q;
        int grow = c * 8 + rsub;
        aP[q] = encBF + (size_t)(bm * 128 + grow) * H + gslot * 8;
        bP[q] = WeT + (size_t)(bn * 128 + grow) * H + gslot * 8;
        aL[q] = &As[c * 512];
        bL[q] = &Bs[c * 512];
    }

    for (int kt = 0; kt < 16; ++kt) {
        if (kt) __syncthreads();
#pragma unroll
        for (int q = 0; q < 4; ++q) gload_lds16(aP[q] + kt * 64, aL[q]);
#pragma unroll
        for (int q = 0; q < 4; ++q) gload_lds16(bP[q] + kt * 64, bL[q]);
        __syncthreads();
#pragma unroll
        for (int kh = 0; kh < 2; ++kh) {
            bf16x8 a[4], bfr[4];
#pragma unroll
            for (int m = 0; m < 4; ++m) {
                int row = wm * 64 + m * 16 + (lane & 15);
                int slot = (kh * 4 + (lane >> 4)) ^ (row & 7);
                a[m] = *(const bf16x8*)&As[row * 64 + slot * 8];
            }
#pragma unroll
            for (int n = 0; n < 4; ++n) {
                int row = wn * 64 + n * 16 + (lane & 15);
                int slot = (kh * 4 + (lane >> 4)) ^ (row & 7);
                bfr[n] = *(const bf16x8*)&Bs[row * 64 + slot * 8];
            }
#pragma unroll
            for (int m = 0; m < 4; ++m)
#pragma unroll
                for (int n = 0; n < 4; ++n)
                    acc[m][n] = __builtin_amdgcn_mfma_f32_16x16x32_bf16(a[m], bfr[n], acc[m][n], 0, 0, 0);
        }
    }

    float vj[4];
#pragma unroll
    for (int n = 0; n < 4; ++n) vj[n] = v[bn * 128 + wn * 64 + n * 16 + (lane & 15)];
    float pv[4][4];
#pragma unroll
    for (int m = 0; m < 4; ++m) {
#pragma unroll
        for (int i = 0; i < 4; ++i) {
            int rg = bm * 128 + wm * 64 + m * 16 + (lane >> 4) * 4 + i;
            int bb = rg & (B - 1);   // row = s*B + b
            float p = 0.f;
#pragma unroll
            for (int n = 0; n < 4; ++n) {
                int j = bn * 128 + wn * 64 + n * 16 + (lane & 15);
                p += vj[n] * tanh_fast(dvec[bb * H + j] + acc[m][n][i]);
            }
            p += __shfl_xor(p, 1);
            p += __shfl_xor(p, 2);
            p += __shfl_xor(p, 4);
            p += __shfl_xor(p, 8);
            pv[m][i] = p;
        }
    }
    __syncthreads();
    float* red = (float*)As;
    if (wn == 1) {
#pragma unroll
        for (int m = 0; m < 4; ++m)
#pragma unroll
            for (int i = 0; i < 4; ++i) {
                int rl = wm * 64 + m * 16 + (lane >> 4) * 4 + i;
                if ((lane & 15) == 0) red[rl] = pv[m][i];
            }
    }
    __syncthreads();
    if (wn == 0) {
#pragma unroll
        for (int m = 0; m < 4; ++m)
#pragma unroll
            for (int i = 0; i < 4; ++i) {
                int rl = wm * 64 + m * 16 + (lane >> 4) * 4 + i;
                int rg = bm * 128 + rl;
                if ((lane & 15) == 0) part[(size_t)rg * 8 + bn] = pv[m][i] + red[rl];
            }
    }
}

// ---------------- softmax over s per b (1024 threads, 2 iters) ----------------
__global__ __launch_bounds__(1024) void softmax_k(const float* __restrict__ part,
                                                  float* __restrict__ scores) {
    int b = blockIdx.x, tid = threadIdx.x;
    int lane = tid & 63, wid = tid >> 6;
    __shared__ float red[16];
    __shared__ float red2[16];
    float lg[2];
    float mx = -1e30f;
#pragma unroll
    for (int q = 0; q < 2; ++q) {
        int s = q * 1024 + tid;
        const float4* pr = (const float4*)(part + ((size_t)(s * B + b)) * 8);
        float4 x = pr[0], y = pr[1];
        float L = ((x.x + x.y) + (x.z + x.w)) + ((y.x + y.y) + (y.z + y.w));
        lg[q] = L;
        mx = fmaxf(mx, L);
    }
#pragma unroll
    for (int off = 32; off; off >>= 1) mx = fmaxf(mx, __shfl_xor(mx, off));
    if (lane == 0) red[wid] = mx;
    __syncthreads();
    mx = red[0];
#pragma unroll
    for (int w = 1; w < 16; ++w) mx = fmaxf(mx, red[w]);
    float sum = 0.f;
#pragma unroll
    for (int q = 0; q < 2; ++q) {
        lg[q] = expf(lg[q] - mx);
        sum += lg[q];
    }
#pragma unroll
    for (int off = 32; off; off >>= 1) sum += __shfl_xor(sum, off);
    if (lane == 0) red2[wid] = sum;
    __syncthreads();
    sum = 0.f;
#pragma unroll
    for (int w = 0; w < 16; ++w) sum += red2[w];
    float inv = 1.f / sum;
#pragma unroll
    for (int q = 0; q < 2; ++q) scores[b * S + q * 1024 + tid] = lg[q] * inv;
}

// ---------------- attn_values partials: float4 over h, 64-s chunks ----------------
__global__ __launch_bounds__(256) void weighted_sum(const float* __restrict__ enc,
                                                    const float* __restrict__ scores,
                                                    float* __restrict__ part2) {
    __shared__ float sl[64];
    int t = threadIdx.x, b = blockIdx.x, sc = blockIdx.y;
    if (t < 64) sl[t] = scores[b * S + sc * 64 + t];
    __syncthreads();
    const float4* ep = (const float4*)(enc + ((size_t)(sc * 64) * B + b) * H) + t;
    float4 a = {0.f, 0.f, 0.f, 0.f};
#pragma unroll 4
    for (int s = 0; s < 64; ++s) {
        float4 e = ep[(size_t)s * B * H / 4];
        float w = sl[s];
        a.x += e.x * w; a.y += e.y * w; a.z += e.z * w; a.w += e.w * w;
    }
    ((float4*)(part2 + ((size_t)sc * B + b) * H))[t] = a;
}

__global__ __launch_bounds__(256) void reduce_vals(const float* __restrict__ part2,
                                                   float* __restrict__ out) {
    int i4 = blockIdx.x * 256 + threadIdx.x;   // over B*H/4 = 8192
    const float4* p4 = (const float4*)part2;
    float4 a = {0.f, 0.f, 0.f, 0.f};
#pragma unroll
    for (int c = 0; c < NSC; ++c) {
        float4 e = p4[(size_t)c * (B * H / 4) + i4];
        a.x += e.x; a.y += e.y; a.z += e.z; a.w += e.w;
    }
    ((float4*)out)[i4] = a;
}

extern "C" void kernel_launch(void* const* d_in, const int* in_sizes, int n_in,
                              void* d_out, int out_size, void* d_ws, size_t ws_size,
                              hipStream_t stream) {
    const float* dec = (const float*)d_in[0];   // [1,B,H]
    const float* enc = (const float*)d_in[1];   // [S,B,H]
    const float* Wd  = (const float*)d_in[2];   // [H,H]
    const float* We  = (const float*)d_in[3];   // [H,H]
    const float* v   = (const float*)d_in[4];   // [H]
    float* out = (float*)d_out;                 // [B*H] values, then [B*S] scores

    // ws layout (dead-buffer overlays, all within proven 136 MB footprint):
    //   part : [0, 2MB)     gemm out -> softmax in
    //   part2: [0, 4MB)     weighted_sum out -> reduce in (overlays dead part)
    //   WeT  : [4MB, 6MB)   prep out -> gemm in (dead once gemm done)
    //   dvec : [6MB, 6.125) prep out -> gemm in
    //   encBF: [8MB, 136MB) prep out -> gemm in
    char* ws = (char*)d_ws;
    float* part  = (float*)ws;
    float* part2 = (float*)ws;
    unsigned short* WeT = (unsigned short*)(ws + (4u << 20));
    float* dvec  = (float*)(ws + (6u << 20));
    unsigned short* encBF = (unsigned short*)(ws + ((size_t)8 << 20));

    prep<<<4480, 256, 0, stream>>>(enc, encBF, We, WeT, dec, Wd, dvec);
    gemm_logits2<<<4096, 256, 0, stream>>>(encBF, WeT, dvec, v, part);
    softmax_k<<<B, 1024, 0, stream>>>(part, out + B * H);
    weighted_sum<<<dim3(B, NSC), 256, 0, stream>>>(enc, out + B * H, part2);
    reduce_vals<<<32, 256, 0, stream>>>(part2, out);
}

// Round 10
// 321.757 us; speedup vs baseline: 1.4773x; 1.1014x over previous
//
#include <hip/hip_runtime.h>

#define H 1024
#define S 2048
#define B 32
#define M (S*B)
#define NSC 32   // S-chunks of 64 for weighted_sum

typedef short bf16x8 __attribute__((ext_vector_type(8)));
typedef float f32x4 __attribute__((ext_vector_type(4)));

__device__ __forceinline__ unsigned short f2bf(float f) {
    unsigned int u = __builtin_bit_cast(unsigned int, f);
    u += 0x7FFFu + ((u >> 16) & 1u);
    return (unsigned short)(u >> 16);
}

__device__ __forceinline__ float bf2f(unsigned short s) {
    unsigned int u = (unsigned int)s << 16;
    return __builtin_bit_cast(float, u);
}

__device__ __forceinline__ float tanh_fast(float x) {
    float e = __expf(2.f * x);
    return 1.f - 2.f / (e + 1.f);
}

__device__ __forceinline__ void gload_lds16(const void* g, void* l) {
    __builtin_amdgcn_global_load_lds((const __attribute__((address_space(1))) void*)g,
                                     (__attribute__((address_space(3))) void*)l, 16, 0, 0);
}

// ---------------- fused prep: convert_enc + transpose_we + dec_proj ----------------
// blocks [0,4096): enc f32->bf16; [4096,4352): We->WeT bf16; [4352,4480): dvec
__global__ __launch_bounds__(256) void prep(const float* __restrict__ enc,
                                            unsigned short* __restrict__ encBF,
                                            const float* __restrict__ We,
                                            unsigned short* __restrict__ WeT,
                                            const float* __restrict__ dec,
                                            const float* __restrict__ Wd,
                                            float* __restrict__ dvec) {
    __shared__ float shbuf[64 * 65];
    int bid = blockIdx.x, t = threadIdx.x;
    if (bid < 4096) {
        const size_t total = (size_t)M * H / 8;
        for (size_t idx = (size_t)bid * 256 + t; idx < total; idx += (size_t)4096 * 256) {
            const float4* p = (const float4*)(enc + idx * 8);
            float4 x = p[0], y = p[1];
            bf16x8 c;
            c[0] = (short)f2bf(x.x); c[1] = (short)f2bf(x.y);
            c[2] = (short)f2bf(x.z); c[3] = (short)f2bf(x.w);
            c[4] = (short)f2bf(y.x); c[5] = (short)f2bf(y.y);
            c[6] = (short)f2bf(y.z); c[7] = (short)f2bf(y.w);
            *(bf16x8*)(encBF + idx * 8) = c;
        }
    } else if (bid < 4352) {
        int b2 = bid - 4096;
        int tx = t & 63, ty = t >> 6;
        int n0 = (b2 & 15) * 64, k0 = (b2 >> 4) * 64;
#pragma unroll
        for (int q = 0; q < 16; ++q) {
            int kk = ty * 16 + q;
            shbuf[kk * 65 + tx] = We[(size_t)(k0 + kk) * H + n0 + tx];
        }
        __syncthreads();
#pragma unroll
        for (int q = 0; q < 16; ++q) {
            int nn = ty * 16 + q;
            WeT[(size_t)(n0 + nn) * H + k0 + tx] = f2bf(shbuf[tx * 65 + nn]);
        }
    } else {
        int b3 = bid - 4352;
        int jc = b3 & 3, b = b3 >> 2;
        for (int i = t; i < H; i += 256) shbuf[i] = dec[b * H + i];
        __syncthreads();
        int j = jc * 256 + t;
        float acc = 0.f;
#pragma unroll 8
        for (int h = 0; h < H; ++h) acc += shbuf[h] * Wd[(size_t)h * H + j];
        dvec[b * H + j] = acc;
    }
}

// ---------------- m97-structure fused GEMM (R8-proven) ----------------
__global__ __launch_bounds__(256) void gemm_logits2(const unsigned short* __restrict__ encBF,
                                                    const unsigned short* __restrict__ WeT,
                                                    const float* __restrict__ dvec,
                                                    const float* __restrict__ v,
                                                    float* __restrict__ part) {
    __shared__ unsigned short As[128 * 64];
    __shared__ unsigned short Bs[128 * 64];
    int tid = threadIdx.x, bid = blockIdx.x;
    int swz = (bid & 7) * 512 + (bid >> 3);   // XCD-chunked, bijective (4096 % 8 == 0)
    int bm = swz >> 3, bn = swz & 7;
    int lane = tid & 63, wid = tid >> 6;
    int wm = wid >> 1, wn = wid & 1;

    f32x4 acc[4][4] = {};

    int rsub = lane >> 3;
    int gslot = (lane & 7) ^ rsub;
    const unsigned short* aP[4];
    const unsigned short* bP[4];
    unsigned short* aL[4];
    unsigned short* bL[4];
#pragma unroll
    for (int q = 0; q < 4; ++q) {
        int c = wid * 4 + q;
        int grow = c * 8 + rsub;
        aP[q] = encBF + (size_t)(bm * 128 + grow) * H + gslot * 8;
        bP[q] = WeT + (size_t)(bn * 128 + grow) * H + gslot * 8;
        aL[q] = &As[c * 512];
        bL[q] = &Bs[c * 512];
    }

    for (int kt = 0; kt < 16; ++kt) {
        if (kt) __syncthreads();
#pragma unroll
        for (int q = 0; q < 4; ++q) gload_lds16(aP[q] + kt * 64, aL[q]);
#pragma unroll
        for (int q = 0; q < 4; ++q) gload_lds16(bP[q] + kt * 64, bL[q]);
        __syncthreads();
#pragma unroll
        for (int kh = 0; kh < 2; ++kh) {
            bf16x8 a[4], bfr[4];
#pragma unroll
            for (int m = 0; m < 4; ++m) {
                int row = wm * 64 + m * 16 + (lane & 15);
                int slot = (kh * 4 + (lane >> 4)) ^ (row & 7);
                a[m] = *(const bf16x8*)&As[row * 64 + slot * 8];
            }
#pragma unroll
            for (int n = 0; n < 4; ++n) {
                int row = wn * 64 + n * 16 + (lane & 15);
                int slot = (kh * 4 + (lane >> 4)) ^ (row & 7);
                bfr[n] = *(const bf16x8*)&Bs[row * 64 + slot * 8];
            }
#pragma unroll
            for (int m = 0; m < 4; ++m)
#pragma unroll
                for (int n = 0; n < 4; ++n)
                    acc[m][n] = __builtin_amdgcn_mfma_f32_16x16x32_bf16(a[m], bfr[n], acc[m][n], 0, 0, 0);
        }
    }

    float vj[4];
#pragma unroll
    for (int n = 0; n < 4; ++n) vj[n] = v[bn * 128 + wn * 64 + n * 16 + (lane & 15)];
    float pv[4][4];
#pragma unroll
    for (int m = 0; m < 4; ++m) {
#pragma unroll
        for (int i = 0; i < 4; ++i) {
            int rg = bm * 128 + wm * 64 + m * 16 + (lane >> 4) * 4 + i;
            int bb = rg & (B - 1);   // row = s*B + b
            float p = 0.f;
#pragma unroll
            for (int n = 0; n < 4; ++n) {
                int j = bn * 128 + wn * 64 + n * 16 + (lane & 15);
                p += vj[n] * tanh_fast(dvec[bb * H + j] + acc[m][n][i]);
            }
            p += __shfl_xor(p, 1);
            p += __shfl_xor(p, 2);
            p += __shfl_xor(p, 4);
            p += __shfl_xor(p, 8);
            pv[m][i] = p;
        }
    }
    __syncthreads();
    float* red = (float*)As;
    if (wn == 1) {
#pragma unroll
        for (int m = 0; m < 4; ++m)
#pragma unroll
            for (int i = 0; i < 4; ++i) {
                int rl = wm * 64 + m * 16 + (lane >> 4) * 4 + i;
                if ((lane & 15) == 0) red[rl] = pv[m][i];
            }
    }
    __syncthreads();
    if (wn == 0) {
#pragma unroll
        for (int m = 0; m < 4; ++m)
#pragma unroll
            for (int i = 0; i < 4; ++i) {
                int rl = wm * 64 + m * 16 + (lane >> 4) * 4 + i;
                int rg = bm * 128 + rl;
                if ((lane & 15) == 0) part[(size_t)rg * 8 + bn] = pv[m][i] + red[rl];
            }
    }
}

// ---------------- softmax over s per b (1024 threads, 2 iters) ----------------
__global__ __launch_bounds__(1024) void softmax_k(const float* __restrict__ part,
                                                  float* __restrict__ scores) {
    int b = blockIdx.x, tid = threadIdx.x;
    int lane = tid & 63, wid = tid >> 6;
    __shared__ float red[16];
    __shared__ float red2[16];
    float lg[2];
    float mx = -1e30f;
#pragma unroll
    for (int q = 0; q < 2; ++q) {
        int s = q * 1024 + tid;
        const float4* pr = (const float4*)(part + ((size_t)(s * B + b)) * 8);
        float4 x = pr[0], y = pr[1];
        float L = ((x.x + x.y) + (x.z + x.w)) + ((y.x + y.y) + (y.z + y.w));
        lg[q] = L;
        mx = fmaxf(mx, L);
    }
#pragma unroll
    for (int off = 32; off; off >>= 1) mx = fmaxf(mx, __shfl_xor(mx, off));
    if (lane == 0) red[wid] = mx;
    __syncthreads();
    mx = red[0];
#pragma unroll
    for (int w = 1; w < 16; ++w) mx = fmaxf(mx, red[w]);
    float sum = 0.f;
#pragma unroll
    for (int q = 0; q < 2; ++q) {
        lg[q] = expf(lg[q] - mx);
        sum += lg[q];
    }
#pragma unroll
    for (int off = 32; off; off >>= 1) sum += __shfl_xor(sum, off);
    if (lane == 0) red2[wid] = sum;
    __syncthreads();
    sum = 0.f;
#pragma unroll
    for (int w = 0; w < 16; ++w) sum += red2[w];
    float inv = 1.f / sum;
#pragma unroll
    for (int q = 0; q < 2; ++q) scores[b * S + q * 1024 + tid] = lg[q] * inv;
}

// ---------------- attn_values partials from bf16 enc (half the HBM traffic) ----------------
__global__ __launch_bounds__(256) void weighted_sum(const unsigned short* __restrict__ encBF,
                                                    const float* __restrict__ scores,
                                                    float* __restrict__ part2) {
    __shared__ float sl[64];
    int t = threadIdx.x, b = blockIdx.x, sc = blockIdx.y;
    if (t < 64) sl[t] = scores[b * S + sc * 64 + t];
    __syncthreads();
    const unsigned short* ep = encBF + ((size_t)(sc * 64) * B + b) * H + t * 4;
    float4 a = {0.f, 0.f, 0.f, 0.f};
#pragma unroll 4
    for (int s = 0; s < 64; ++s) {
        ushort4 e = *(const ushort4*)(ep + (size_t)s * B * H);
        float w = sl[s];
        a.x += bf2f(e.x) * w;
        a.y += bf2f(e.y) * w;
        a.z += bf2f(e.z) * w;
        a.w += bf2f(e.w) * w;
    }
    ((float4*)(part2 + ((size_t)sc * B + b) * H))[t] = a;
}

__global__ __launch_bounds__(256) void reduce_vals(const float* __restrict__ part2,
                                                   float* __restrict__ out) {
    int i4 = blockIdx.x * 256 + threadIdx.x;   // over B*H/4 = 8192
    const float4* p4 = (const float4*)part2;
    float4 a = {0.f, 0.f, 0.f, 0.f};
#pragma unroll
    for (int c = 0; c < NSC; ++c) {
        float4 e = p4[(size_t)c * (B * H / 4) + i4];
        a.x += e.x; a.y += e.y; a.z += e.z; a.w += e.w;
    }
    ((float4*)out)[i4] = a;
}

extern "C" void kernel_launch(void* const* d_in, const int* in_sizes, int n_in,
                              void* d_out, int out_size, void* d_ws, size_t ws_size,
                              hipStream_t stream) {
    const float* dec = (const float*)d_in[0];   // [1,B,H]
    const float* enc = (const float*)d_in[1];   // [S,B,H]
    const float* Wd  = (const float*)d_in[2];   // [H,H]
    const float* We  = (const float*)d_in[3];   // [H,H]
    const float* v   = (const float*)d_in[4];   // [H]
    float* out = (float*)d_out;                 // [B*H] values, then [B*S] scores

    // ws layout (dead-buffer overlays):
    //   part : [0, 2MB)     gemm out -> softmax in
    //   part2: [0, 4MB)     weighted_sum out -> reduce in (overlays dead part)
    //   WeT  : [4MB, 6MB)   prep out -> gemm in
    //   dvec : [6MB, 6.125) prep out -> gemm in
    //   encBF: [8MB, 136MB) prep out -> gemm + weighted_sum in
    char* ws = (char*)d_ws;
    float* part  = (float*)ws;
    float* part2 = (float*)ws;
    unsigned short* WeT = (unsigned short*)(ws + (4u << 20));
    float* dvec  = (float*)(ws + (6u << 20));
    unsigned short* encBF = (unsigned short*)(ws + ((size_t)8 << 20));

    prep<<<4480, 256, 0, stream>>>(enc, encBF, We, WeT, dec, Wd, dvec);
    gemm_logits2<<<4096, 256, 0, stream>>>(encBF, WeT, dvec, v, part);
    softmax_k<<<B, 1024, 0, stream>>>(part, out + B * H);
    weighted_sum<<<dim3(B, NSC), 256, 0, stream>>>(encBF, out + B * H, part2);
    reduce_vals<<<32, 256, 0, stream>>>(part2, out);
}

// Round 12
// 298.716 us; speedup vs baseline: 1.5912x; 1.0771x over previous
//
#include <hip/hip_runtime.h>

#define H 1024
#define S 2048
#define B 32
#define M (S*B)
#define NSC 32   // S-chunks of 64 for weighted_sum (each split in 2 internally)

typedef short bf16x8 __attribute__((ext_vector_type(8)));
typedef float f32x4 __attribute__((ext_vector_type(4)));

__device__ __forceinline__ unsigned short f2bf(float f) {
    unsigned int u = __builtin_bit_cast(unsigned int, f);
    u += 0x7FFFu + ((u >> 16) & 1u);
    return (unsigned short)(u >> 16);
}

__device__ __forceinline__ float bf2f(unsigned short s) {
    unsigned int u = (unsigned int)s << 16;
    return __builtin_bit_cast(float, u);
}

__device__ __forceinline__ float tanh_fast(float x) {
    float e = __expf(2.f * x);
    return 1.f - 2.f / (e + 1.f);
}

__device__ __forceinline__ void gload_lds16(const void* g, void* l) {
    __builtin_amdgcn_global_load_lds((const __attribute__((address_space(1))) void*)g,
                                     (__attribute__((address_space(3))) void*)l, 16, 0, 0);
}

// ---------------- fused prep: convert_enc + transpose_we + dec_proj ----------------
// blocks [0,4096): enc f32->bf16 (nt loads: f32 enc is never re-read);
// [4096,4352): We->WeT bf16; [4352,4480): dvec
__global__ __launch_bounds__(256) void prep(const float* __restrict__ enc,
                                            unsigned short* __restrict__ encBF,
                                            const float* __restrict__ We,
                                            unsigned short* __restrict__ WeT,
                                            const float* __restrict__ dec,
                                            const float* __restrict__ Wd,
                                            float* __restrict__ dvec) {
    __shared__ float shbuf[64 * 65];
    int bid = blockIdx.x, t = threadIdx.x;
    if (bid < 4096) {
        const size_t total = (size_t)M * H / 8;
        for (size_t idx = (size_t)bid * 256 + t; idx < total; idx += (size_t)4096 * 256) {
            const f32x4* p = (const f32x4*)(enc + idx * 8);
            f32x4 x = __builtin_nontemporal_load(p);
            f32x4 y = __builtin_nontemporal_load(p + 1);
            bf16x8 c;
            c[0] = (short)f2bf(x[0]); c[1] = (short)f2bf(x[1]);
            c[2] = (short)f2bf(x[2]); c[3] = (short)f2bf(x[3]);
            c[4] = (short)f2bf(y[0]); c[5] = (short)f2bf(y[1]);
            c[6] = (short)f2bf(y[2]); c[7] = (short)f2bf(y[3]);
            *(bf16x8*)(encBF + idx * 8) = c;
        }
    } else if (bid < 4352) {
        int b2 = bid - 4096;
        int tx = t & 63, ty = t >> 6;
        int n0 = (b2 & 15) * 64, k0 = (b2 >> 4) * 64;
#pragma unroll
        for (int q = 0; q < 16; ++q) {
            int kk = ty * 16 + q;
            shbuf[kk * 65 + tx] = We[(size_t)(k0 + kk) * H + n0 + tx];
        }
        __syncthreads();
#pragma unroll
        for (int q = 0; q < 16; ++q) {
            int nn = ty * 16 + q;
            WeT[(size_t)(n0 + nn) * H + k0 + tx] = f2bf(shbuf[tx * 65 + nn]);
        }
    } else {
        int b3 = bid - 4352;
        int jc = b3 & 3, b = b3 >> 2;
        for (int i = t; i < H; i += 256) shbuf[i] = dec[b * H + i];
        __syncthreads();
        int j = jc * 256 + t;
        float acc = 0.f;
#pragma unroll 8
        for (int h = 0; h < H; ++h) acc += shbuf[h] * Wd[(size_t)h * H + j];
        dvec[b * H + j] = acc;
    }
}

// ---------------- m97-structure fused GEMM (R8-proven) ----------------
__global__ __launch_bounds__(256) void gemm_logits2(const unsigned short* __restrict__ encBF,
                                                    const unsigned short* __restrict__ WeT,
                                                    const float* __restrict__ dvec,
                                                    const float* __restrict__ v,
                                                    float* __restrict__ part) {
    __shared__ unsigned short As[128 * 64];
    __shared__ unsigned short Bs[128 * 64];
    int tid = threadIdx.x, bid = blockIdx.x;
    int swz = (bid & 7) * 512 + (bid >> 3);   // XCD-chunked, bijective (4096 % 8 == 0)
    int bm = swz >> 3, bn = swz & 7;
    int lane = tid & 63, wid = tid >> 6;
    int wm = wid >> 1, wn = wid & 1;

    f32x4 acc[4][4] = {};

    int rsub = lane >> 3;
    int gslot = (lane & 7) ^ rsub;
    const unsigned short* aP[4];
    const unsigned short* bP[4];
    unsigned short* aL[4];
    unsigned short* bL[4];
#pragma unroll
    for (int q = 0; q < 4; ++q) {
        int c = wid * 4 + q;
        int grow = c * 8 + rsub;
        aP[q] = encBF + (size_t)(bm * 128 + grow) * H + gslot * 8;
        bP[q] = WeT + (size_t)(bn * 128 + grow) * H + gslot * 8;
        aL[q] = &As[c * 512];
        bL[q] = &Bs[c * 512];
    }

    for (int kt = 0; kt < 16; ++kt) {
        if (kt) __syncthreads();
#pragma unroll
        for (int q = 0; q < 4; ++q) gload_lds16(aP[q] + kt * 64, aL[q]);
#pragma unroll
        for (int q = 0; q < 4; ++q) gload_lds16(bP[q] + kt * 64, bL[q]);
        __syncthreads();
#pragma unroll
        for (int kh = 0; kh < 2; ++kh) {
            bf16x8 a[4], bfr[4];
#pragma unroll
            for (int m = 0; m < 4; ++m) {
                int row = wm * 64 + m * 16 + (lane & 15);
                int slot = (kh * 4 + (lane >> 4)) ^ (row & 7);
                a[m] = *(const bf16x8*)&As[row * 64 + slot * 8];
            }
#pragma unroll
            for (int n = 0; n < 4; ++n) {
                int row = wn * 64 + n * 16 + (lane & 15);
                int slot = (kh * 4 + (lane >> 4)) ^ (row & 7);
                bfr[n] = *(const bf16x8*)&Bs[row * 64 + slot * 8];
            }
#pragma unroll
            for (int m = 0; m < 4; ++m)
#pragma unroll
                for (int n = 0; n < 4; ++n)
                    acc[m][n] = __builtin_amdgcn_mfma_f32_16x16x32_bf16(a[m], bfr[n], acc[m][n], 0, 0, 0);
        }
    }

    float vj[4];
#pragma unroll
    for (int n = 0; n < 4; ++n) vj[n] = v[bn * 128 + wn * 64 + n * 16 + (lane & 15)];
    float pv[4][4];
#pragma unroll
    for (int m = 0; m < 4; ++m) {
#pragma unroll
        for (int i = 0; i < 4; ++i) {
            int rg = bm * 128 + wm * 64 + m * 16 + (lane >> 4) * 4 + i;
            int bb = rg & (B - 1);   // row = s*B + b
            float p = 0.f;
#pragma unroll
            for (int n = 0; n < 4; ++n) {
                int j = bn * 128 + wn * 64 + n * 16 + (lane & 15);
                p += vj[n] * tanh_fast(dvec[bb * H + j] + acc[m][n][i]);
            }
            p += __shfl_xor(p, 1);
            p += __shfl_xor(p, 2);
            p += __shfl_xor(p, 4);
            p += __shfl_xor(p, 8);
            pv[m][i] = p;
        }
    }
    __syncthreads();
    float* red = (float*)As;
    if (wn == 1) {
#pragma unroll
        for (int m = 0; m < 4; ++m)
#pragma unroll
            for (int i = 0; i < 4; ++i) {
                int rl = wm * 64 + m * 16 + (lane >> 4) * 4 + i;
                if ((lane & 15) == 0) red[rl] = pv[m][i];
            }
    }
    __syncthreads();
    if (wn == 0) {
#pragma unroll
        for (int m = 0; m < 4; ++m)
#pragma unroll
            for (int i = 0; i < 4; ++i) {
                int rl = wm * 64 + m * 16 + (lane >> 4) * 4 + i;
                int rg = bm * 128 + rl;
                if ((lane & 15) == 0) part[(size_t)rg * 8 + bn] = pv[m][i] + red[rl];
            }
    }
}

// ---------------- softmax over s per b (1024 threads, 2 iters) ----------------
__global__ __launch_bounds__(1024) void softmax_k(const float* __restrict__ part,
                                                  float* __restrict__ scores) {
    int b = blockIdx.x, tid = threadIdx.x;
    int lane = tid & 63, wid = tid >> 6;
    __shared__ float red[16];
    __shared__ float red2[16];
    float lg[2];
    float mx = -1e30f;
#pragma unroll
    for (int q = 0; q < 2; ++q) {
        int s = q * 1024 + tid;
        const float4* pr = (const float4*)(part + ((size_t)(s * B + b)) * 8);
        float4 x = pr[0], y = pr[1];
        float L = ((x.x + x.y) + (x.z + x.w)) + ((y.x + y.y) + (y.z + y.w));
        lg[q] = L;
        mx = fmaxf(mx, L);
    }
#pragma unroll
    for (int off = 32; off; off >>= 1) mx = fmaxf(mx, __shfl_xor(mx, off));
    if (lane == 0) red[wid] = mx;
    __syncthreads();
    mx = red[0];
#pragma unroll
    for (int w = 1; w < 16; ++w) mx = fmaxf(mx, red[w]);
    float sum = 0.f;
#pragma unroll
    for (int q = 0; q < 2; ++q) {
        lg[q] = expf(lg[q] - mx);
        sum += lg[q];
    }
#pragma unroll
    for (int off = 32; off; off >>= 1) sum += __shfl_xor(sum, off);
    if (lane == 0) red2[wid] = sum;
    __syncthreads();
    sum = 0.f;
#pragma unroll
    for (int w = 0; w < 16; ++w) sum += red2[w];
    float inv = 1.f / sum;
#pragma unroll
    for (int q = 0; q < 2; ++q) scores[b * S + q * 1024 + tid] = lg[q] * inv;
}

// ---------------- attn_values partials: bf16x8 (16 B/lane), 32-s subchunks ----------------
__global__ __launch_bounds__(256) void weighted_sum(const unsigned short* __restrict__ encBF,
                                                    const float* __restrict__ scores,
                                                    float* __restrict__ part2) {
    __shared__ float sl[64];
    int t = threadIdx.x, b = blockIdx.x, sc = blockIdx.y;
    if (t < 64) sl[t] = scores[b * S + sc * 64 + t];
    __syncthreads();
    int half = t >> 7;            // 0/1: which 32-s subchunk
    int hx = (t & 127) * 8;       // h offset (bf16x8 = 16 B)
    const unsigned short* ep = encBF + ((size_t)(sc * 64 + half * 32) * B + b) * H + hx;
    float a[8] = {};
#pragma unroll 4
    for (int s = 0; s < 32; ++s) {
        bf16x8 e = *(const bf16x8*)(ep + (size_t)s * B * H);
        float w = sl[half * 32 + s];
#pragma unroll
        for (int k = 0; k < 8; ++k) a[k] += bf2f((unsigned short)e[k]) * w;
    }
    float4* dst = (float4*)(part2 + ((size_t)(sc * 2 + half) * B + b) * H + hx);
    dst[0] = make_float4(a[0], a[1], a[2], a[3]);
    dst[1] = make_float4(a[4], a[5], a[6], a[7]);
}

__global__ __launch_bounds__(256) void reduce_vals(const float* __restrict__ part2,
                                                   float* __restrict__ out) {
    int i4 = blockIdx.x * 256 + threadIdx.x;   // over B*H/4 = 8192
    const float4* p4 = (const float4*)part2;
    float4 a = {0.f, 0.f, 0.f, 0.f};
#pragma unroll
    for (int c = 0; c < 2 * NSC; ++c) {
        float4 e = p4[(size_t)c * (B * H / 4) + i4];
        a.x += e.x; a.y += e.y; a.z += e.z; a.w += e.w;
    }
    ((float4*)out)[i4] = a;
}

extern "C" void kernel_launch(void* const* d_in, const int* in_sizes, int n_in,
                              void* d_out, int out_size, void* d_ws, size_t ws_size,
                              hipStream_t stream) {
    const float* dec = (const float*)d_in[0];   // [1,B,H]
    const float* enc = (const float*)d_in[1];   // [S,B,H]
    const float* Wd  = (const float*)d_in[2];   // [H,H]
    const float* We  = (const float*)d_in[3];   // [H,H]
    const float* v   = (const float*)d_in[4];   // [H]
    float* out = (float*)d_out;                 // [B*H] values, then [B*S] scores

    // ws layout (dead-buffer overlays):
    //   part : [0, 2MB)      gemm out -> softmax in (dead after softmax)
    //   part2: [0, 8MB)      weighted_sum out -> reduce in (overlays part/WeT/dvec,
    //                        all dead once weighted_sum runs)
    //   WeT  : [4MB, 6MB)    prep out -> gemm in
    //   dvec : [6MB, 6.125)  prep out -> gemm in
    //   encBF: [8MB, 136MB)  prep out -> gemm + weighted_sum in
    char* ws = (char*)d_ws;
    float* part  = (float*)ws;
    float* part2 = (float*)ws;
    unsigned short* WeT = (unsigned short*)(ws + (4u << 20));
    float* dvec  = (float*)(ws + (6u << 20));
    unsigned short* encBF = (unsigned short*)(ws + ((size_t)8 << 20));

    prep<<<4480, 256, 0, stream>>>(enc, encBF, We, WeT, dec, Wd, dvec);
    gemm_logits2<<<4096, 256, 0, stream>>>(encBF, WeT, dvec, v, part);
    softmax_k<<<B, 1024, 0, stream>>>(part, out + B * H);
    weighted_sum<<<dim3(B, NSC), 256, 0, stream>>>(encBF, out + B * H, part2);
    reduce_vals<<<32, 256, 0, stream>>>(part2, out);
}